// Round 14
// baseline (57.568 us; speedup 1.0000x reference)
//
#include <hip/hip_runtime.h>

typedef unsigned short u16;
typedef __bf16 bf16x8 __attribute__((ext_vector_type(8)));
typedef float f32x4 __attribute__((ext_vector_type(4)));

#define B_   16
#define H_   56
#define W_   56
#define C_   128
#define OH_  54
#define OW_  54
#define NF_  256
#define KF_  1152           // C_*9
#define M_   46656          // B_*OH_*OW_
#define NNZ_ 58982
#define WT_ELEMS (KF_*NF_)  // 294912, image [k/8][col][8]

__device__ __forceinline__ u16 f2bf(float f) {
    unsigned u = __float_as_uint(f);
    u += 0x7FFFu + ((u >> 16) & 1u);
    return (u16)(u >> 16);
}

__device__ __forceinline__ void gload16(const void* g, void* l) {
    __builtin_amdgcn_global_load_lds(
        (const __attribute__((address_space(1))) unsigned int*)g,
        (__attribute__((address_space(3))) unsigned int*)l,
        16, 0, 0);
}

// ---- kernel 1: scatter sparse values into W image [k/8][col][8] ----
// step kt reads elems kt*8192..+8191 (k-window kt*32..+31, all 256 cols).
__global__ __launch_bounds__(256) void scatter_kernel(const float* __restrict__ kv,
                                                      const int* __restrict__ idx,
                                                      u16* __restrict__ wt) {
    int t = blockIdx.x * 256 + threadIdx.x;
    if (t >= NNZ_) return;
    int k   = idx[2*t];      // row in [0,1152)
    int col = idx[2*t + 1];  // col in [0,256)
    wt[(k >> 3) * 2048 + col * 8 + (k & 7)] = f2bf(kv[t]);
}

// ---- kernel 2: strip-resident-A implicit GEMM ----
// 1 block = 1 output row: 864 blocks (=16 img x 54 rows), 256 thr = 4 waves,
// wave tile 64(pad of 54) x 64 cols, BK=32, 36 steps.
// A: x-strip (3 in-rows x 56 x 128) loaded ONCE f32->bf16 into LDS (43KB),
//    chunk-XOR c^(jj&7) swizzle; every K-step's A-frag is an LDS offset
//    (im2col tap) -> ZERO A re-fetch through L2.
// B: pre-tiled wt, 16KB/step via 4 gload_lds/thread, 2-deep counted vmcnt(4).
// LDS 75776B -> 2 blocks/CU (8 waves/CU). Per-SIMD/step: MFMA ~620 cyc vs
// B-ingest ~600 cyc (previous rounds: 80KB/step ingest-serialized at 25%).
__global__ __launch_bounds__(256, 2) void spconv_gemm(const float* __restrict__ x,
                                                      const u16* __restrict__ wt,
                                                      const float* __restrict__ bias,
                                                      float* __restrict__ out) {
    __shared__ __align__(16) u16 strip[21504];   // 42 KB [pix 168][chunk16^jj][8]
    __shared__ __align__(16) u16 Bs[2][8192];    // 2 x 16 KB [chunk4][col256][8]

    const int t    = threadIdx.x;
    const int lane = t & 63;
    const int w    = t >> 6;          // wave 0..3 -> col quarter
    const int ks   = lane >> 4;       // k-group 0..3
    const int r16  = lane & 15;

    // XCD swizzle (864 % 8 == 0 -> simple bijective form); consecutive wg on
    // one XCD are consecutive orow -> strips overlap 2/3 rows -> L2-hot.
    const int wg   = (blockIdx.x & 7) * 108 + (blockIdx.x >> 3);
    const int bb   = wg / 54;
    const int orow = wg % 54;
    const float* xbase = x + (size_t)((bb * 56 + orow) * 56) * 128;

    // ---- prologue: stage strip (2688 cells of 8 elems), f32 -> bf16 ----
    for (int cid = t; cid < 2688; cid += 256) {
        int xr  = cid / 896;          // input row 0..2
        int rem = cid % 896;
        int jj  = rem >> 4;           // 0..55
        int c   = rem & 15;           // chunk 0..15
        const float* s = xbase + (xr * 56 + jj) * 128 + c * 8;
        float4 v0 = *(const float4*)s;
        float4 v1 = *(const float4*)(s + 4);
        union { u16 u[8]; uint4 v; } r;
        r.u[0] = f2bf(v0.x); r.u[1] = f2bf(v0.y); r.u[2] = f2bf(v0.z); r.u[3] = f2bf(v0.w);
        r.u[4] = f2bf(v1.x); r.u[5] = f2bf(v1.y); r.u[6] = f2bf(v1.z); r.u[7] = f2bf(v1.w);
        *(uint4*)&strip[((xr * 56 + jj) * 16 + (c ^ (jj & 7))) * 8] = r.v;
    }

    // per-lane A row (clamped: pad rows 54..63 read row 53, never written)
    int jmin[4];
#pragma unroll
    for (int mf = 0; mf < 4; ++mf)
        jmin[mf] = min(mf * 16 + r16, 53);

    f32x4 acc[4][4];
    const f32x4 zz = {0.f, 0.f, 0.f, 0.f};
#pragma unroll
    for (int i = 0; i < 4; ++i)
#pragma unroll
        for (int j = 0; j < 4; ++j) acc[i][j] = zz;

#define ISSUE_B(kt, bi) do {                                                \
    const u16* bsrc_ = wt + (kt) * 8192 + t * 8;                            \
    gload16(bsrc_,        &Bs[bi][t * 8]);                                  \
    gload16(bsrc_ + 2048, &Bs[bi][t * 8 + 2048]);                           \
    gload16(bsrc_ + 4096, &Bs[bi][t * 8 + 4096]);                           \
    gload16(bsrc_ + 6144, &Bs[bi][t * 8 + 6144]);                           \
} while (0)

#define COMPUTE(bi, DI, DJ, KW) do {                                        \
    bf16x8 bfr_[4];                                                         \
    _Pragma("unroll")                                                       \
    for (int nf = 0; nf < 4; ++nf)                                          \
        bfr_[nf] = *(const bf16x8*)(&Bs[bi][(ks * 256 + w * 64 + nf * 16 + r16) * 8]); \
    _Pragma("unroll")                                                       \
    for (int mf = 0; mf < 4; ++mf) {                                        \
        int jjl_ = jmin[mf] + (DJ);                                         \
        bf16x8 af_ = *(const bf16x8*)(&strip[((DI) * 56 + jjl_) * 128 +     \
                                             (((KW) * 4 + ks) ^ (jjl_ & 7)) * 8]); \
        acc[mf][0] = __builtin_amdgcn_mfma_f32_16x16x32_bf16(af_, bfr_[0], acc[mf][0], 0, 0, 0); \
        acc[mf][1] = __builtin_amdgcn_mfma_f32_16x16x32_bf16(af_, bfr_[1], acc[mf][1], 0, 0, 0); \
        acc[mf][2] = __builtin_amdgcn_mfma_f32_16x16x32_bf16(af_, bfr_[2], acc[mf][2], 0, 0, 0); \
        acc[mf][3] = __builtin_amdgcn_mfma_f32_16x16x32_bf16(af_, bfr_[3], acc[mf][3], 0, 0, 0); \
    }                                                                       \
} while (0)

#define WAITVM(n) asm volatile("s_waitcnt vmcnt(" #n ")" ::: "memory")
#define BAR() do { __builtin_amdgcn_s_barrier();                            \
                   asm volatile("" ::: "memory"); } while (0)

    // strip visible to all waves; drains prologue loads too
    __syncthreads();

    // 2 B-tiles in flight
    ISSUE_B(0, 0);
    ISSUE_B(1, 1);

    // main loop: iters 0..33 issue tiles 2..35; vmcnt never drains mid-loop
#pragma unroll
    for (int k = 0; k < 34; ++k) {
        int g  = k >> 2;
        int di = (g * 11) >> 5;       // g/3 for g<9
        int dj = g - 3 * di;
        WAITVM(4);                    // own tile-k loads landed
        BAR();                        // all waves' tile-k staging visible
        COMPUTE(k & 1, di, dj, k & 3);
        BAR();                        // all waves consumed Bs[k&1]
        ISSUE_B(k + 2, k & 1);
    }
    // tail: k = 34 (g=8: di=2,dj=2,kw=2), k = 35 (kw=3)
    WAITVM(4); BAR(); COMPUTE(0, 2, 2, 2); BAR();
    WAITVM(0); BAR(); COMPUTE(1, 2, 2, 3);

#undef ISSUE_B
#undef COMPUTE
#undef WAITVM
#undef BAR

    // epilogue: C/D layout col=lane&15, row=(lane>>4)*4+reg (m89-verified)
    const int opix0 = (bb * 54 + orow) * 54;
#pragma unroll
    for (int nf = 0; nf < 4; ++nf) {
        int col  = w * 64 + nf * 16 + r16;
        float bv = bias[col];
#pragma unroll
        for (int mf = 0; mf < 4; ++mf) {
#pragma unroll
            for (int rr = 0; rr < 4; ++rr) {
                int ml = mf * 16 + ks * 4 + rr;
                if (ml < 54) {
                    float v = acc[mf][nf][rr] + bv;
                    out[(opix0 + ml) * NF_ + col] = fmaxf(v, 0.f);
                }
            }
        }
    }
}

extern "C" void kernel_launch(void* const* d_in, const int* in_sizes, int n_in,
                              void* d_out, int out_size, void* d_ws, size_t ws_size,
                              hipStream_t stream) {
    const float* x    = (const float*)d_in[0];
    const float* kv   = (const float*)d_in[1];
    const float* bias = (const float*)d_in[2];
    const int*   idx  = (const int*)d_in[3];
    float* out = (float*)d_out;

    u16* wtp = (u16*)d_ws;

    hipMemsetAsync(wtp, 0, (size_t)WT_ELEMS * 2, stream);
    scatter_kernel<<<(NNZ_ + 255) / 256, 256, 0, stream>>>(kv, idx, wtp);
    spconv_gemm<<<864, 256, 0, stream>>>(x, wtp, bias, out);
}

// Round 15
// 47.597 us; speedup vs baseline: 1.2095x; 1.2095x over previous
//
#include <hip/hip_runtime.h>

typedef unsigned short u16;
typedef __bf16 bf16x8 __attribute__((ext_vector_type(8)));
typedef float f32x4 __attribute__((ext_vector_type(4)));

#define B_   16
#define H_   56
#define W_   56
#define C_   128
#define OH_  54
#define OW_  54
#define NF_  256
#define KF_  1152           // C_*9
#define M_   46656          // B_*OH_*OW_
#define NNZ_ 58982

#define XB_ELEMS (B_*H_*W_*C_)       // 6422528
#define WT_ELEMS (KF_*NF_)           // 294912, image [k/8][col][8]

__device__ __forceinline__ u16 f2bf(float f) {
    unsigned u = __float_as_uint(f);
    u += 0x7FFFu + ((u >> 16) & 1u);
    return (u16)(u >> 16);
}

__device__ __forceinline__ void gload16(const void* g, void* l) {
    __builtin_amdgcn_global_load_lds(
        (const __attribute__((address_space(1))) unsigned int*)g,
        (__attribute__((address_space(3))) unsigned int*)l,
        16, 0, 0);
}

// ---- kernel 1: x f32 -> bf16 (8/thread) + fused zeroing of wt ----
__global__ __launch_bounds__(256) void cvt_x_kernel(const float* __restrict__ x,
                                                    u16* __restrict__ xb,
                                                    u16* __restrict__ wt) {
    if (blockIdx.x < 144) {
        uint4 z = {0u, 0u, 0u, 0u};
        ((uint4*)wt)[blockIdx.x * 256 + threadIdx.x] = z;
    }
    int i = (blockIdx.x * 256 + threadIdx.x) * 8;
    float4 v0 = *(const float4*)(x + i);
    float4 v1 = *(const float4*)(x + i + 4);
    union { u16 u[8]; uint4 v; } r;
    r.u[0] = f2bf(v0.x); r.u[1] = f2bf(v0.y); r.u[2] = f2bf(v0.z); r.u[3] = f2bf(v0.w);
    r.u[4] = f2bf(v1.x); r.u[5] = f2bf(v1.y); r.u[6] = f2bf(v1.z); r.u[7] = f2bf(v1.w);
    *(uint4*)(xb + i) = r.v;
}

// ---- kernel 2: scatter sparse values into W image [k/8][col][8] ----
__global__ __launch_bounds__(256) void scatter_kernel(const float* __restrict__ kv,
                                                      const int* __restrict__ idx,
                                                      u16* __restrict__ wt) {
    int t = blockIdx.x * 256 + threadIdx.x;
    if (t >= NNZ_) return;
    int k   = idx[2*t];      // row in [0,1152)
    int col = idx[2*t + 1];  // col in [0,256)
    wt[(k >> 3) * 2048 + col * 8 + (k & 7)] = f2bf(kv[t]);
}

// ---- kernel 3: 192x256 implicit GEMM, 3-deep ring, 2-step prefetch ----
// 243 blocks (exact, 1/CU), 512 thr = 8 waves (2M x 4N), wave tile 96x64,
// BK=32 -> 36 steps of 28KB staged. LDS: A 3x12KB [row192][slot4^f(row)][8],
// B 3x16KB [ch4][col256][8] -> 84KB. Role-split staging: waves 0-3 stage A
// (3 gload_lds), waves 4-7 stage B (4 gload_lds); counted vmcnt(3)/(4).
// KEY: ISSUE(k+2) BEFORE COMPUTE(k) -> every load issued 2 full steps
// (~1000+ cyc) before its wait deadline, covering L3/HBM latency at
// 1 block/CU (R12/R13's 1-phase distance was the failure).
__global__ __launch_bounds__(512) void spconv_gemm(const u16* __restrict__ xb,
                                                   const u16* __restrict__ wt,
                                                   const float* __restrict__ bias,
                                                   float* __restrict__ out) {
    __shared__ __align__(16) u16 As[3][192 * 4 * 8];   // 3 x 12 KB
    __shared__ __align__(16) u16 Bs[3][4 * 256 * 8];   // 3 x 16 KB

    const int t    = threadIdx.x;     // 0..511
    const int l    = t & 63;
    const int w    = t >> 6;          // wave 0..7
    const int r16  = l & 15;
    const int ks   = l >> 4;          // 0..3
    const int wr   = w >> 2;          // 0..1 (96-row half)
    const int wc   = w & 3;           // 0..3 (64-col quarter)

    // bijective XCD swizzle (nwg=243 -> m204)
    const int nwg = gridDim.x;
    const int q = nwg >> 3, rr_ = nwg & 7;
    const int xcd = blockIdx.x & 7, inner = blockIdx.x >> 3;
    const int wg = (xcd < rr_ ? xcd * (q + 1) : rr_ * (q + 1) + (xcd - rr_) * q) + inner;
    const int m0 = wg * 192;

    // A staging (threads 0..255): cell u=(row=u>>2, sd=u&3); stages rows
    // r0, r0+64, r0+128 (f(row) invariant across +64). Src chunk = sd^f(r0).
    const int ua  = t & 255;
    const int r0  = ua >> 2;
    const int kco = (((ua & 3) ^ (r0 & 3) ^ ((r0 >> 2) & 3))) * 8;
    const u16* a_base[3];
#pragma unroll
    for (int j = 0; j < 3; ++j) {
        int mg  = m0 + r0 + j * 64;
        int bb  = mg / (OH_ * OW_);
        int rem = mg % (OH_ * OW_);
        int ii  = rem / OW_;
        int jj  = rem % OW_;
        a_base[j] = xb + ((bb * H_ + ii) * W_ + jj) * C_;
    }

    f32x4 acc[6][4];
    const f32x4 zz = {0.f, 0.f, 0.f, 0.f};
#pragma unroll
    for (int i = 0; i < 6; ++i)
#pragma unroll
        for (int j = 0; j < 4; ++j) acc[i][j] = zz;

    const int cidx = ks ^ (r16 & 3) ^ ((r16 >> 2) & 3);   // mf/wr-invariant

#define ISSUE(kt, bi) do {                                                  \
    if (t < 256) {                                                          \
        int g_  = (kt) >> 2;                                                \
        int di_ = (g_ * 11) >> 5;                                           \
        int dj_ = g_ - 3 * di_;                                             \
        int aoff_ = (di_ * W_ + dj_) * C_ + ((kt) & 3) * 32 + kco;          \
        gload16(a_base[0] + aoff_, &As[bi][t * 8]);                         \
        gload16(a_base[1] + aoff_, &As[bi][(t + 256) * 8]);                 \
        gload16(a_base[2] + aoff_, &As[bi][(t + 512) * 8]);                 \
    } else {                                                                \
        const u16* bsrc_ = wt + (kt) * 8192 + (t - 256) * 8;                \
        gload16(bsrc_,        &Bs[bi][(t - 256) * 8]);                      \
        gload16(bsrc_ + 2048, &Bs[bi][(t - 256) * 8 + 2048]);               \
        gload16(bsrc_ + 4096, &Bs[bi][(t - 256) * 8 + 4096]);               \
        gload16(bsrc_ + 6144, &Bs[bi][(t - 256) * 8 + 6144]);               \
    }                                                                       \
} while (0)

#define COMPUTE(bi) do {                                                    \
    bf16x8 bfr_[4];                                                         \
    _Pragma("unroll")                                                       \
    for (int nf = 0; nf < 4; ++nf)                                          \
        bfr_[nf] = *(const bf16x8*)(&Bs[bi][(ks * 256 + wc * 64 + nf * 16 + r16) * 8]); \
    _Pragma("unroll")                                                       \
    for (int mf = 0; mf < 6; ++mf) {                                        \
        int row_ = wr * 96 + mf * 16 + r16;                                 \
        bf16x8 af_ = *(const bf16x8*)(&As[bi][(row_ * 4 + cidx) * 8]);      \
        acc[mf][0] = __builtin_amdgcn_mfma_f32_16x16x32_bf16(af_, bfr_[0], acc[mf][0], 0, 0, 0); \
        acc[mf][1] = __builtin_amdgcn_mfma_f32_16x16x32_bf16(af_, bfr_[1], acc[mf][1], 0, 0, 0); \
        acc[mf][2] = __builtin_amdgcn_mfma_f32_16x16x32_bf16(af_, bfr_[2], acc[mf][2], 0, 0, 0); \
        acc[mf][3] = __builtin_amdgcn_mfma_f32_16x16x32_bf16(af_, bfr_[3], acc[mf][3], 0, 0, 0); \
    }                                                                       \
} while (0)

// per-role counted waits (A-role 3 loads/step in flight, B-role 4)
#define WAITVM(na, nb) do {                                                 \
    if (t < 256) { asm volatile("s_waitcnt vmcnt(" #na ")" ::: "memory"); } \
    else         { asm volatile("s_waitcnt vmcnt(" #nb ")" ::: "memory"); } \
} while (0)
#define BAR() do { __builtin_amdgcn_s_barrier();                            \
                   asm volatile("" ::: "memory"); } while (0)

    // prologue: tiles 0,1 in flight
    ISSUE(0, 0);
    ISSUE(1, 1);

    // main loop: k = 0..33, ISSUE(k+2) BEFORE COMPUTE(k). At the wait,
    // outstanding = tile k+1 only (3/4 loads); tile k's loads were issued
    // 2 steps ago. Unroll x3 keeps all buffer indices compile-time.
#pragma unroll
    for (int k3 = 0; k3 < 11; ++k3) {
        int k = 3 * k3;
        WAITVM(3, 4); BAR(); ISSUE(k + 2, (k + 2) % 3); COMPUTE(0); BAR();
        WAITVM(3, 4); BAR(); ISSUE(k + 3, (k + 3) % 3); COMPUTE(1); BAR();
        if (k3 < 10) {
            WAITVM(3, 4); BAR(); ISSUE(k + 4, (k + 4) % 3); COMPUTE(2); BAR();
        }
    }
    // k=32 (last issue: tile 34? no — tiles end at 35; k=32 issues 34? 
    // Ledger: loop above covered k=0..31 issuing tiles 2..33. Remaining:
    // k=32 (issue 34), k=33 (issue 35), k=34, k=35.
    WAITVM(3, 4); BAR(); ISSUE(34, 1); COMPUTE(2); BAR();   // k=32, buf 32%3=2
    WAITVM(3, 4); BAR(); ISSUE(35, 2); COMPUTE(0); BAR();   // k=33, buf 0
    WAITVM(3, 4); BAR(); COMPUTE(1); BAR();                 // k=34, buf 1
    WAITVM(0, 0); BAR(); COMPUTE(2);                        // k=35, buf 2

#undef ISSUE
#undef COMPUTE
#undef WAITVM
#undef BAR

    // epilogue: C/D layout col = lane&15, row = (lane>>4)*4 + reg (m89-verified)
#pragma unroll
    for (int nf = 0; nf < 4; ++nf) {
        int col  = wc * 64 + nf * 16 + r16;
        float bv = bias[col];
#pragma unroll
        for (int mf = 0; mf < 6; ++mf) {
#pragma unroll
            for (int rg = 0; rg < 4; ++rg) {
                int row = m0 + wr * 96 + mf * 16 + ks * 4 + rg;
                float v = acc[mf][nf][rg] + bv;
                out[row * NF_ + col] = fmaxf(v, 0.f);
            }
        }
    }
}

extern "C" void kernel_launch(void* const* d_in, const int* in_sizes, int n_in,
                              void* d_out, int out_size, void* d_ws, size_t ws_size,
                              hipStream_t stream) {
    const float* x    = (const float*)d_in[0];
    const float* kv   = (const float*)d_in[1];
    const float* bias = (const float*)d_in[2];
    const int*   idx  = (const int*)d_in[3];
    float* out = (float*)d_out;

    u16* xb  = (u16*)d_ws;
    u16* wtp = (u16*)((char*)d_ws + (size_t)XB_ELEMS * 2);

    cvt_x_kernel<<<XB_ELEMS / (256 * 8), 256, 0, stream>>>(x, xb, wtp);
    scatter_kernel<<<(NNZ_ + 255) / 256, 256, 0, stream>>>(kv, idx, wtp);
    spconv_gemm<<<M_ / 192, 512, 0, stream>>>(xb, wtp, bias, out);
}

// Round 18
// 45.389 us; speedup vs baseline: 1.2683x; 1.0487x over previous
//
#include <hip/hip_runtime.h>

typedef unsigned short u16;
typedef __bf16 bf16x8 __attribute__((ext_vector_type(8)));
typedef float f32x4 __attribute__((ext_vector_type(4)));

#define B_   16
#define H_   56
#define W_   56
#define C_   128
#define OH_  54
#define OW_  54
#define NF_  256
#define KF_  1152           // C_*9
#define M_   46656          // B_*OH_*OW_
#define NNZ_ 58982

#define XB_ELEMS (B_*H_*W_*C_)       // 6422528
#define WT_ELEMS (KF_*NF_)           // 294912, image [k/8][col][8]

__device__ __forceinline__ u16 f2bf(float f) {
    unsigned u = __float_as_uint(f);
    u += 0x7FFFu + ((u >> 16) & 1u);
    return (u16)(u >> 16);
}

__device__ __forceinline__ void gload16(const void* g, void* l) {
    __builtin_amdgcn_global_load_lds(
        (const __attribute__((address_space(1))) unsigned int*)g,
        (__attribute__((address_space(3))) unsigned int*)l,
        16, 0, 0);
}

// ---- kernel 1: fused x f32->bf16 (8/thread) + sparse scatter into wt ----
// wt pre-zeroed by hipMemsetAsync (stream-ordered before this kernel).
// Blocks 0..230 additionally scatter one pair per thread (gt < NNZ_).
__global__ __launch_bounds__(256) void cvt_scatter_kernel(const float* __restrict__ x,
                                                          u16* __restrict__ xb,
                                                          const float* __restrict__ kv,
                                                          const int* __restrict__ idx,
                                                          u16* __restrict__ wt) {
    int gt = blockIdx.x * 256 + threadIdx.x;
    if (gt < NNZ_) {
        int k   = idx[2*gt];      // row in [0,1152)
        int col = idx[2*gt + 1];  // col in [0,256)
        wt[(k >> 3) * 2048 + col * 8 + (k & 7)] = f2bf(kv[gt]);
    }
    int i = gt * 8;
    float4 v0 = *(const float4*)(x + i);
    float4 v1 = *(const float4*)(x + i + 4);
    union { u16 u[8]; uint4 v; } r;
    r.u[0] = f2bf(v0.x); r.u[1] = f2bf(v0.y); r.u[2] = f2bf(v0.z); r.u[3] = f2bf(v0.w);
    r.u[4] = f2bf(v1.x); r.u[5] = f2bf(v1.y); r.u[6] = f2bf(v1.z); r.u[7] = f2bf(v1.w);
    *(uint4*)(xb + i) = r.v;
}

// ---- kernel 2: 3-deep pipelined implicit GEMM (R10-verified, verbatim) ----
// grid 729 (BM=64), 4 waves, wave tile 64x64, BK=32, 36 phases.
// A: LDS 3-deep 3x4KB row-major [row][slot^f(row)][8] (XOR on global source,
//    lane-linear gload_lds dest); staged 1 gload_lds/thread.
// B: registers 3-deep (3 named sets x 4 frags), 4 global_load_dwordx4/thread
//    from the wt image; issued BEFORE the MFMA cluster (writes set (k+2)%3,
//    no conflict with set k%3 being read -> issue hides under MFMA).
// Uniform 5 vmem/thread/phase; steady counted vmcnt(6); >=2-phase load cover.
__global__ __launch_bounds__(256, 3) void spconv_gemm(const u16* __restrict__ xb,
                                                      const u16* __restrict__ wt,
                                                      const float* __restrict__ bias,
                                                      float* __restrict__ out) {
    __shared__ __align__(16) u16 As[3][64 * 32];   // 3 x 4 KB

    const int t    = threadIdx.x;
    const int lane = t & 63;
    const int wid  = t >> 6;

    // bijective XCD swizzle (nwg=729 -> m204 formula)
    const int nwg = gridDim.x;
    const int q = nwg >> 3, r = nwg & 7;
    const int xcd = blockIdx.x & 7, inner = blockIdx.x >> 3;
    const int wg = (xcd < r ? xcd * (q + 1) : r * (q + 1) + (xcd - r) * q) + inner;
    const int m0 = wg * 64;

    // A staging: cell t = (row=t>>2, sd=t&3); src chunk = sd ^ f(row),
    // f(row) = (row&3)^((row>>2)&3). 4 lanes/row -> 64B sectors.
    const int arow = t >> 2;
    const int kco  = ((t & 3) ^ (arow & 3) ^ ((arow >> 2) & 3)) * 8;
    const u16* a_base;
    {
        int mg  = m0 + arow;
        int bb  = mg / (OH_ * OW_);
        int rem = mg % (OH_ * OW_);
        int ii  = rem / OW_;
        int jj  = rem % OW_;
        a_base = xb + ((bb * H_ + ii) * W_ + jj) * C_;
    }

    const int ks   = lane >> 4;
    const int r16  = lane & 15;
    const int cidx = ks ^ (r16 & 3) ^ ((r16 >> 2) & 3);   // mf-invariant

    // B: per-lane base into wt image (bytes); per tile advance 16384B.
    const char* bptr = (const char*)wt + ks * 4096 + (wid * 64 + r16) * 16;

    f32x4 acc[4][4];
    const f32x4 zz = {0.f, 0.f, 0.f, 0.f};
#pragma unroll
    for (int i = 0; i < 4; ++i)
#pragma unroll
        for (int j = 0; j < 4; ++j) acc[i][j] = zz;

    bf16x8 bs[3][4];   // 3-deep B regsets (indices constant after unroll)

#define LOADB(dst, base, imm) \
    asm volatile("global_load_dwordx4 %0, %1, off offset:" imm \
                 : "=v"(dst) : "v"(base))

#define ISSUE_B(si) do {                                                    \
    LOADB(bs[si][0], bptr, "0");   LOADB(bs[si][1], bptr, "256");           \
    LOADB(bs[si][2], bptr, "512"); LOADB(bs[si][3], bptr, "768");           \
    bptr += 16384;                                                          \
} while (0)

#define ISSUE_A(kn, bi) do {                                                \
    int g_  = (kn) >> 2;                                                    \
    int di_ = (g_ * 11) >> 5;                                               \
    int dj_ = g_ - 3 * di_;                                                 \
    int aoff_ = (di_ * W_ + dj_) * C_ + ((kn) & 3) * 32 + kco;              \
    gload16(a_base + aoff_, &As[bi][t * 8]);                                \
} while (0)

#define COMPUTE(bi, si) do {                                                \
    bf16x8 a0_ = *(const bf16x8*)(&As[bi][(r16) * 32 + cidx * 8]);          \
    bf16x8 a1_ = *(const bf16x8*)(&As[bi][(16 + r16) * 32 + cidx * 8]);     \
    bf16x8 a2_ = *(const bf16x8*)(&As[bi][(32 + r16) * 32 + cidx * 8]);     \
    bf16x8 a3_ = *(const bf16x8*)(&As[bi][(48 + r16) * 32 + cidx * 8]);     \
    _Pragma("unroll")                                                       \
    for (int nf = 0; nf < 4; ++nf) {                                        \
        acc[0][nf] = __builtin_amdgcn_mfma_f32_16x16x32_bf16(a0_, bs[si][nf], acc[0][nf], 0, 0, 0); \
        acc[1][nf] = __builtin_amdgcn_mfma_f32_16x16x32_bf16(a1_, bs[si][nf], acc[1][nf], 0, 0, 0); \
        acc[2][nf] = __builtin_amdgcn_mfma_f32_16x16x32_bf16(a2_, bs[si][nf], acc[2][nf], 0, 0, 0); \
        acc[3][nf] = __builtin_amdgcn_mfma_f32_16x16x32_bf16(a3_, bs[si][nf], acc[3][nf], 0, 0, 0); \
    }                                                                       \
} while (0)

#define WAITVM(n) asm volatile("s_waitcnt vmcnt(" #n ")" ::: "memory")
#define BAR() do { __builtin_amdgcn_s_barrier();                            \
                   asm volatile("" ::: "memory"); } while (0)

    // prologue: [B0, A0, B1, A1, A2] -> 11 vmem in flight
    ISSUE_B(0);
    ISSUE_A(0, 0);
    ISSUE_B(1);
    ISSUE_A(1, 1);
    ISSUE_A(2, 2);

    // phases 0..32 (full): wait(6) drains tile-k A+B; issue B(k+2), A(k+3)
#pragma unroll
    for (int k = 0; k < 33; ++k) {
        WAITVM(6); BAR();
        ISSUE_B((k + 2) % 3);         // constant after unroll
        COMPUTE(k % 3, k % 3);
        BAR();
        ISSUE_A(k + 3, k % 3);
    }
    // phase 33: issue B35 only
    WAITVM(6); BAR();
    ISSUE_B(2);
    COMPUTE(0, 0);
    BAR();
    // phase 34
    WAITVM(5); BAR();
    COMPUTE(1, 1);
    // phase 35
    WAITVM(0); BAR();
    COMPUTE(2, 2);

#undef LOADB
#undef ISSUE_B
#undef ISSUE_A
#undef COMPUTE
#undef WAITVM
#undef BAR

    // epilogue: C/D layout col = lane&15, row = (lane>>4)*4 + reg (m89-verified)
    const int rgrp = lane >> 4;
#pragma unroll
    for (int nf = 0; nf < 4; ++nf) {
        int col  = wid * 64 + nf * 16 + r16;
        float bv = bias[col];
#pragma unroll
        for (int mf = 0; mf < 4; ++mf) {
#pragma unroll
            for (int rr = 0; rr < 4; ++rr) {
                int row = m0 + mf * 16 + rgrp * 4 + rr;
                float v = acc[mf][nf][rr] + bv;
                out[row * NF_ + col] = fmaxf(v, 0.f);
            }
        }
    }
}

extern "C" void kernel_launch(void* const* d_in, const int* in_sizes, int n_in,
                              void* d_out, int out_size, void* d_ws, size_t ws_size,
                              hipStream_t stream) {
    const float* x    = (const float*)d_in[0];
    const float* kv   = (const float*)d_in[1];
    const float* bias = (const float*)d_in[2];
    const int*   idx  = (const int*)d_in[3];
    float* out = (float*)d_out;

    u16* xb  = (u16*)d_ws;
    u16* wtp = (u16*)((char*)d_ws + (size_t)XB_ELEMS * 2);

    hipMemsetAsync(wtp, 0, (size_t)WT_ELEMS * 2, stream);
    cvt_scatter_kernel<<<XB_ELEMS / (256 * 8), 256, 0, stream>>>(x, xb, kv, idx, wtp);
    spconv_gemm<<<M_ / 64, 256, 0, stream>>>(xb, wtp, bias, out);
}